// Round 1
// baseline (3219.999 us; speedup 1.0000x reference)
//
#include <hip/hip_runtime.h>

#define NF 64

// tanhshrink(x) = x - tanh(x);  tanh(x) = 1 - 2/(exp(2x)+1)
__device__ __forceinline__ float ts_f(float x){
  float t = __expf(2.0f*x);
  float th = 1.0f - 2.0f*__builtin_amdgcn_rcpf(t + 1.0f);
  return x - th;
}
__device__ __forceinline__ float sigmoid_f(float x){
  return __builtin_amdgcn_rcpf(1.0f + __expf(-x));
}

// One lane per edge. k-outer / j-inner matvecs: activations stream from
// global (or per-wave LDS scratch for intermediates), weights are wave-uniform
// scalar loads, 64 accumulators live in VGPRs (fully unrolled j).
__global__ __launch_bounds__(256, 2) void egcl_edge(
    const float* __restrict__ nodes, const float* __restrict__ coord,
    const int*   __restrict__ edges,
    const float* __restrict__ eW1, const float* __restrict__ eb1,
    const float* __restrict__ eW2, const float* __restrict__ eb2,
    const float* __restrict__ aW1, const float* __restrict__ ab1,
    const float* __restrict__ aW2, const float* __restrict__ ab2,
    const float* __restrict__ cW1, const float* __restrict__ cb1,
    const float* __restrict__ cW2, const float* __restrict__ cb2,
    float* __restrict__ agg_out, float* __restrict__ coord_out,
    int E)
{
  __shared__ float buf[4][NF][NF];           // [wave][k][lane] per-lane scratch, 64 KB
  const int tid  = threadIdx.x;
  const int wid  = tid >> 6;
  const int lane = tid & 63;
  const int e = blockIdx.x * 256 + tid;
  if (e >= E) return;

  const int r = edges[e];
  const int c = edges[E + e];

  const float rx = coord[3*r+0] - coord[3*c+0];
  const float ry = coord[3*r+1] - coord[3*c+1];
  const float rz = coord[3*r+2] - coord[3*c+2];
  const float radial = rx*rx + ry*ry + rz*rz;

  // ---- phase 1: h1 preact (eW1, K=129) and a1 preact (aW1, K=128), fused X stream
  float acch[NF], acca[NF];
  #pragma unroll
  for (int j=0;j<NF;j++) acch[j] = eb1[j] + radial * eW1[128*NF + j];
  #pragma unroll
  for (int j=0;j<NF;j++) acca[j] = ab1[j];

  const float* __restrict__ srow = nodes + (size_t)r * NF;
  const float* __restrict__ trow = nodes + (size_t)c * NF - 64;  // used for q>=16
  #pragma unroll 1
  for (int q=0;q<32;q++){
    const float* b = (q < 16) ? srow : trow;
    const float4 xv = *(const float4*)(b + 4*q);
    const float xs[4] = {xv.x, xv.y, xv.z, xv.w};
    #pragma unroll
    for (int u=0;u<4;u++){
      const int k = 4*q + u;
      const float xk = xs[u];
      const float* __restrict__ w1 = eW1 + k*NF;
      const float* __restrict__ w2 = aW1 + k*NF;
      #pragma unroll
      for (int j=0;j<NF;j++){
        acch[j] = fmaf(xk, w1[j], acch[j]);
        acca[j] = fmaf(xk, w2[j], acca[j]);
      }
    }
  }

  // ---- attention gate: a = sigmoid(ts(a1) . aW2 + ab2)
  float sp0=0.f, sp1=0.f, sp2=0.f, sp3=0.f;
  #pragma unroll
  for (int j=0;j<NF;j+=4){
    sp0 += ts_f(acca[j+0]) * aW2[j+0];
    sp1 += ts_f(acca[j+1]) * aW2[j+1];
    sp2 += ts_f(acca[j+2]) * aW2[j+2];
    sp3 += ts_f(acca[j+3]) * aW2[j+3];
  }
  const float gate = sigmoid_f(sp0+sp1+sp2+sp3 + ab2[0]);

  // ---- h1 = ts(acch) -> LDS scratch (runtime-k reads need memory, not regs)
  #pragma unroll
  for (int j=0;j<NF;j++) buf[wid][j][lane] = ts_f(acch[j]);

  // ---- phase 2: h2 preact (eW2, K=64)
  float acc2[NF];
  #pragma unroll
  for (int j=0;j<NF;j++) acc2[j] = eb2[j];
  #pragma unroll 1
  for (int kq=0;kq<16;kq++){
    #pragma unroll
    for (int ku=0;ku<4;ku++){
      const int k = kq*4+ku;
      const float hk = buf[wid][k][lane];
      const float* __restrict__ w = eW2 + k*NF;
      #pragma unroll
      for (int j=0;j<NF;j++) acc2[j] = fmaf(hk, w[j], acc2[j]);
    }
  }

  // ---- edge_feat = ts(h2)*gate : store to LDS (for cW1) + scatter atomics
  float* __restrict__ aggrow = agg_out + (size_t)r * NF;
  #pragma unroll
  for (int j=0;j<NF;j++){
    const float efj = ts_f(acc2[j]) * gate;
    buf[wid][j][lane] = efj;
    atomicAdd(aggrow + j, efj);
  }

  // ---- phase 3: c1 preact (cW1, K=64), then cs = ts(c1).cW2 + cb2
  float acc3[NF];
  #pragma unroll
  for (int j=0;j<NF;j++) acc3[j] = cb1[j];
  #pragma unroll 1
  for (int kq=0;kq<16;kq++){
    #pragma unroll
    for (int ku=0;ku<4;ku++){
      const int k = kq*4+ku;
      const float ek = buf[wid][k][lane];
      const float* __restrict__ w = cW1 + k*NF;
      #pragma unroll
      for (int j=0;j<NF;j++) acc3[j] = fmaf(ek, w[j], acc3[j]);
    }
  }
  float c0=0.f, c1s=0.f, c2s=0.f, c3s=0.f;
  #pragma unroll
  for (int j=0;j<NF;j+=4){
    c0  += ts_f(acc3[j+0]) * cW2[j+0];
    c1s += ts_f(acc3[j+1]) * cW2[j+1];
    c2s += ts_f(acc3[j+2]) * cW2[j+2];
    c3s += ts_f(acc3[j+3]) * cW2[j+3];
  }
  const float cs = c0+c1s+c2s+c3s + cb2[0];
  atomicAdd(coord_out + 3*r + 0, rx * cs);
  atomicAdd(coord_out + 3*r + 1, ry * cs);
  atomicAdd(coord_out + 3*r + 2, rz * cs);
}

// One lane per node. agg was accumulated (by atomics) directly into
// out_nodes; each lane reads its own row then overwrites it (no race).
__global__ __launch_bounds__(256, 2) void egcl_node(
    const float* __restrict__ nodes, const float* __restrict__ coord,
    const float* __restrict__ nW1, const float* __restrict__ nb1,
    const float* __restrict__ nW2, const float* __restrict__ nb2,
    float* __restrict__ out_nodes, float* __restrict__ out_coord,
    int N)
{
  __shared__ float buf[4][NF][NF];
  const int tid = threadIdx.x, wid = tid>>6, lane = tid&63;
  const int i = blockIdx.x*256 + tid;
  if (i >= N) return;

  float acc[NF];
  #pragma unroll
  for (int j=0;j<NF;j++) acc[j] = nb1[j];

  const float* __restrict__ xrow = nodes     + (size_t)i*NF;
  const float* __restrict__ grow = out_nodes + (size_t)i*NF - 64;  // agg, q>=16
  #pragma unroll 1
  for (int q=0;q<32;q++){
    const float* b = (q<16) ? xrow : grow;
    const float4 xv = *(const float4*)(b + 4*q);
    const float xs[4] = {xv.x,xv.y,xv.z,xv.w};
    #pragma unroll
    for (int u=0;u<4;u++){
      const int k = 4*q+u;
      const float xk = xs[u];
      const float* __restrict__ w = nW1 + k*NF;
      #pragma unroll
      for (int j=0;j<NF;j++) acc[j] = fmaf(xk, w[j], acc[j]);
    }
  }

  #pragma unroll
  for (int j=0;j<NF;j++) buf[wid][j][lane] = ts_f(acc[j]);

  float acc2[NF];
  #pragma unroll
  for (int j=0;j<NF;j++) acc2[j] = nb2[j];
  #pragma unroll 1
  for (int kq=0;kq<16;kq++){
    #pragma unroll
    for (int ku=0;ku<4;ku++){
      const int k = kq*4+ku;
      const float mk = buf[wid][k][lane];
      const float* __restrict__ w = nW2 + k*NF;
      #pragma unroll
      for (int j=0;j<NF;j++) acc2[j] = fmaf(mk, w[j], acc2[j]);
    }
  }

  float* __restrict__ orow = out_nodes + (size_t)i*NF;
  #pragma unroll
  for (int q=0;q<16;q++){
    const float4 xv = *(const float4*)(xrow + 4*q);
    float4 o;
    o.x = xv.x + acc2[4*q+0];
    o.y = xv.y + acc2[4*q+1];
    o.z = xv.z + acc2[4*q+2];
    o.w = xv.w + acc2[4*q+3];
    *(float4*)(orow + 4*q) = o;
  }

  const int b3 = 3*i;
  out_coord[b3+0] += coord[b3+0];
  out_coord[b3+1] += coord[b3+1];
  out_coord[b3+2] += coord[b3+2];
}

extern "C" void kernel_launch(void* const* d_in, const int* in_sizes, int n_in,
                              void* d_out, int out_size, void* d_ws, size_t ws_size,
                              hipStream_t stream)
{
  const float* nodes = (const float*)d_in[0];
  const float* coord = (const float*)d_in[1];
  const int*   edges = (const int*)  d_in[2];
  const float* eW1 = (const float*)d_in[3];
  const float* eb1 = (const float*)d_in[4];
  const float* eW2 = (const float*)d_in[5];
  const float* eb2 = (const float*)d_in[6];
  const float* aW1 = (const float*)d_in[7];
  const float* ab1 = (const float*)d_in[8];
  const float* aW2 = (const float*)d_in[9];
  const float* ab2 = (const float*)d_in[10];
  const float* nW1 = (const float*)d_in[11];
  const float* nb1 = (const float*)d_in[12];
  const float* nW2 = (const float*)d_in[13];
  const float* nb2 = (const float*)d_in[14];
  const float* cW1 = (const float*)d_in[15];
  const float* cb1 = (const float*)d_in[16];
  const float* cW2 = (const float*)d_in[17];
  const float* cb2 = (const float*)d_in[18];

  const int E = in_sizes[2] / 2;       // 800000
  const int N = in_sizes[0] / NF;      // 50000
  float* out_nodes = (float*)d_out;                      // also agg accumulator
  float* out_coord = out_nodes + (size_t)N * NF;         // also trans accumulator

  hipMemsetAsync(d_out, 0, (size_t)out_size * sizeof(float), stream);

  egcl_edge<<<(E + 255)/256, 256, 0, stream>>>(nodes, coord, edges,
      eW1, eb1, eW2, eb2, aW1, ab1, aW2, ab2, cW1, cb1, cW2, cb2,
      out_nodes, out_coord, E);

  egcl_node<<<(N + 255)/256, 256, 0, stream>>>(nodes, coord,
      nW1, nb1, nW2, nb2, out_nodes, out_coord, N);
}

// Round 2
// 1462.250 us; speedup vs baseline: 2.2021x; 2.2021x over previous
//
#include <hip/hip_runtime.h>

#define NF 64

// tanhshrink(x) = x - tanh(x);  tanh(x) = 1 - 2/(exp(2x)+1)
__device__ __forceinline__ float ts_f(float x){
  float t = __expf(2.0f*x);
  float th = 1.0f - 2.0f*__builtin_amdgcn_rcpf(t + 1.0f);
  return x - th;
}
__device__ __forceinline__ float sigmoid_f(float x){
  return __builtin_amdgcn_rcpf(1.0f + __expf(-x));
}

// One wave per block, one lane per edge. k-outer / j-inner matvecs:
// X (node rows) stream through VGPRs, weights are wave-uniform scalar loads,
// 64 accumulators in VGPRs. One 64x65 LDS tile (pad -> all patterns 2-way,
// free) serves as h1 scratch [k][lane], then edge_feat [j][lane]; the agg
// scatter reads it column-wise (buf[lane][e]) so each atomic instruction
// hits ONE node row with 64 consecutive dwords (4 lines vs 64 per-lane).
__global__ __launch_bounds__(64, 4) void egcl_edge(
    const float* __restrict__ nodes, const float* __restrict__ coord,
    const int*   __restrict__ edges,
    const float* __restrict__ eW1, const float* __restrict__ eb1,
    const float* __restrict__ eW2, const float* __restrict__ eb2,
    const float* __restrict__ aW1, const float* __restrict__ ab1,
    const float* __restrict__ aW2, const float* __restrict__ ab2,
    const float* __restrict__ cW1, const float* __restrict__ cb1,
    const float* __restrict__ cW2, const float* __restrict__ cb2,
    float* __restrict__ agg_out, float* __restrict__ coord_out,
    int E)
{
  __shared__ float buf[NF][NF+1];   // 16.64 KB: [feature][edge-lane]
  __shared__ int   rbuf[64];
  const int lane = threadIdx.x;
  const int e = blockIdx.x * 64 + lane;
  const bool valid = (e < E);
  const int el = valid ? e : (E - 1);

  const int r = edges[el];
  const int c = edges[E + el];
  rbuf[lane] = valid ? r : -1;

  const float rx = coord[3*r+0] - coord[3*c+0];
  const float ry = coord[3*r+1] - coord[3*c+1];
  const float rz = coord[3*r+2] - coord[3*c+2];
  const float radial = rx*rx + ry*ry + rz*rz;

  // ---- phase 1: h1 preact (eW1, K=129) and a1 preact (aW1, K=128), fused X stream
  float acch[NF], acca[NF];
  #pragma unroll
  for (int j=0;j<NF;j++) acch[j] = eb1[j] + radial * eW1[128*NF + j];
  #pragma unroll
  for (int j=0;j<NF;j++) acca[j] = ab1[j];

  const float* __restrict__ srow = nodes + (size_t)r * NF;
  const float* __restrict__ trow = nodes + (size_t)c * NF - 64;  // used for q>=16
  #pragma unroll 1
  for (int q=0;q<32;q++){
    const float* b = (q < 16) ? srow : trow;
    const float4 xv = *(const float4*)(b + 4*q);
    const float xs[4] = {xv.x, xv.y, xv.z, xv.w};
    #pragma unroll
    for (int u=0;u<4;u++){
      const int k = 4*q + u;
      const float xk = xs[u];
      const float* __restrict__ w1 = eW1 + k*NF;
      const float* __restrict__ w2 = aW1 + k*NF;
      #pragma unroll
      for (int j=0;j<NF;j++){
        acch[j] = fmaf(xk, w1[j], acch[j]);
        acca[j] = fmaf(xk, w2[j], acca[j]);
      }
    }
  }

  // ---- attention gate: a = sigmoid(ts(a1) . aW2 + ab2)
  float sp0=0.f, sp1=0.f, sp2=0.f, sp3=0.f;
  #pragma unroll
  for (int j=0;j<NF;j+=4){
    sp0 += ts_f(acca[j+0]) * aW2[j+0];
    sp1 += ts_f(acca[j+1]) * aW2[j+1];
    sp2 += ts_f(acca[j+2]) * aW2[j+2];
    sp3 += ts_f(acca[j+3]) * aW2[j+3];
  }
  const float gate = sigmoid_f(sp0+sp1+sp2+sp3 + ab2[0]);

  // ---- h1 = ts(acch) -> LDS scratch [k][lane]
  #pragma unroll
  for (int j=0;j<NF;j++) buf[j][lane] = ts_f(acch[j]);
  __syncthreads();

  // ---- phase 2: h2 preact (eW2, K=64)
  float acc2[NF];
  #pragma unroll
  for (int j=0;j<NF;j++) acc2[j] = eb2[j];
  #pragma unroll 1
  for (int kq=0;kq<16;kq++){
    #pragma unroll
    for (int ku=0;ku<4;ku++){
      const int k = kq*4+ku;
      const float hk = buf[k][lane];
      const float* __restrict__ w = eW2 + k*NF;
      #pragma unroll
      for (int j=0;j<NF;j++) acc2[j] = fmaf(hk, w[j], acc2[j]);
    }
  }
  __syncthreads();

  // ---- edge_feat = ts(h2)*gate -> LDS [j][lane]
  #pragma unroll
  for (int j=0;j<NF;j++) buf[j][lane] = ts_f(acc2[j]) * gate;
  __syncthreads();

  // ---- cooperative coalesced agg scatter: per edge eo, all 64 lanes add
  // consecutive dwords of row r[eo]. Issued BEFORE phase-3 FMAs so the
  // (fire-and-forget) atomics drain under compute.
  #pragma unroll 1
  for (int eo=0;eo<64;eo++){
    const int rr = rbuf[eo];
    if (rr >= 0)
      atomicAdd(agg_out + (size_t)rr * NF + lane, buf[lane][eo]);
  }

  // ---- phase 3: c1 preact (cW1, K=64) from LDS ef, then cs = ts(c1).cW2 + cb2
  float acc3[NF];
  #pragma unroll
  for (int j=0;j<NF;j++) acc3[j] = cb1[j];
  #pragma unroll 1
  for (int kq=0;kq<16;kq++){
    #pragma unroll
    for (int ku=0;ku<4;ku++){
      const int k = kq*4+ku;
      const float ek = buf[k][lane];
      const float* __restrict__ w = cW1 + k*NF;
      #pragma unroll
      for (int j=0;j<NF;j++) acc3[j] = fmaf(ek, w[j], acc3[j]);
    }
  }
  float c0=0.f, c1s=0.f, c2s=0.f, c3s=0.f;
  #pragma unroll
  for (int j=0;j<NF;j+=4){
    c0  += ts_f(acc3[j+0]) * cW2[j+0];
    c1s += ts_f(acc3[j+1]) * cW2[j+1];
    c2s += ts_f(acc3[j+2]) * cW2[j+2];
    c3s += ts_f(acc3[j+3]) * cW2[j+3];
  }
  const float cs = c0+c1s+c2s+c3s + cb2[0];
  if (valid){
    atomicAdd(coord_out + 3*r + 0, rx * cs);
    atomicAdd(coord_out + 3*r + 1, ry * cs);
    atomicAdd(coord_out + 3*r + 2, rz * cs);
  }
}

// One lane per node. agg was accumulated (by atomics) directly into
// out_nodes; each lane reads its own row then overwrites it (no race).
__global__ __launch_bounds__(256, 2) void egcl_node(
    const float* __restrict__ nodes, const float* __restrict__ coord,
    const float* __restrict__ nW1, const float* __restrict__ nb1,
    const float* __restrict__ nW2, const float* __restrict__ nb2,
    float* __restrict__ out_nodes, float* __restrict__ out_coord,
    int N)
{
  __shared__ float buf[4][NF][NF+1];
  const int tid = threadIdx.x, wid = tid>>6, lane = tid&63;
  const int i = blockIdx.x*256 + tid;
  if (i >= N) return;

  float acc[NF];
  #pragma unroll
  for (int j=0;j<NF;j++) acc[j] = nb1[j];

  const float* __restrict__ xrow = nodes     + (size_t)i*NF;
  const float* __restrict__ grow = out_nodes + (size_t)i*NF - 64;  // agg, q>=16
  #pragma unroll 1
  for (int q=0;q<32;q++){
    const float* b = (q<16) ? xrow : grow;
    const float4 xv = *(const float4*)(b + 4*q);
    const float xs[4] = {xv.x,xv.y,xv.z,xv.w};
    #pragma unroll
    for (int u=0;u<4;u++){
      const int k = 4*q+u;
      const float xk = xs[u];
      const float* __restrict__ w = nW1 + k*NF;
      #pragma unroll
      for (int j=0;j<NF;j++) acc[j] = fmaf(xk, w[j], acc[j]);
    }
  }

  #pragma unroll
  for (int j=0;j<NF;j++) buf[wid][j][lane] = ts_f(acc[j]);

  float acc2[NF];
  #pragma unroll
  for (int j=0;j<NF;j++) acc2[j] = nb2[j];
  #pragma unroll 1
  for (int kq=0;kq<16;kq++){
    #pragma unroll
    for (int ku=0;ku<4;ku++){
      const int k = kq*4+ku;
      const float mk = buf[wid][k][lane];
      const float* __restrict__ w = nW2 + k*NF;
      #pragma unroll
      for (int j=0;j<NF;j++) acc2[j] = fmaf(mk, w[j], acc2[j]);
    }
  }

  float* __restrict__ orow = out_nodes + (size_t)i*NF;
  #pragma unroll
  for (int q=0;q<16;q++){
    const float4 xv = *(const float4*)(xrow + 4*q);
    float4 o;
    o.x = xv.x + acc2[4*q+0];
    o.y = xv.y + acc2[4*q+1];
    o.z = xv.z + acc2[4*q+2];
    o.w = xv.w + acc2[4*q+3];
    *(float4*)(orow + 4*q) = o;
  }

  const int b3 = 3*i;
  out_coord[b3+0] += coord[b3+0];
  out_coord[b3+1] += coord[b3+1];
  out_coord[b3+2] += coord[b3+2];
}

extern "C" void kernel_launch(void* const* d_in, const int* in_sizes, int n_in,
                              void* d_out, int out_size, void* d_ws, size_t ws_size,
                              hipStream_t stream)
{
  const float* nodes = (const float*)d_in[0];
  const float* coord = (const float*)d_in[1];
  const int*   edges = (const int*)  d_in[2];
  const float* eW1 = (const float*)d_in[3];
  const float* eb1 = (const float*)d_in[4];
  const float* eW2 = (const float*)d_in[5];
  const float* eb2 = (const float*)d_in[6];
  const float* aW1 = (const float*)d_in[7];
  const float* ab1 = (const float*)d_in[8];
  const float* aW2 = (const float*)d_in[9];
  const float* ab2 = (const float*)d_in[10];
  const float* nW1 = (const float*)d_in[11];
  const float* nb1 = (const float*)d_in[12];
  const float* nW2 = (const float*)d_in[13];
  const float* nb2 = (const float*)d_in[14];
  const float* cW1 = (const float*)d_in[15];
  const float* cb1 = (const float*)d_in[16];
  const float* cW2 = (const float*)d_in[17];
  const float* cb2 = (const float*)d_in[18];

  const int E = in_sizes[2] / 2;       // 800000
  const int N = in_sizes[0] / NF;      // 50000
  float* out_nodes = (float*)d_out;                      // also agg accumulator
  float* out_coord = out_nodes + (size_t)N * NF;         // also trans accumulator

  hipMemsetAsync(d_out, 0, (size_t)out_size * sizeof(float), stream);

  egcl_edge<<<(E + 63)/64, 64, 0, stream>>>(nodes, coord, edges,
      eW1, eb1, eW2, eb2, aW1, ab1, aW2, ab2, cW1, cb1, cW2, cb2,
      out_nodes, out_coord, E);

  egcl_node<<<(N + 255)/256, 256, 0, stream>>>(nodes, coord,
      nW1, nb1, nW2, nb2, out_nodes, out_coord, N);
}

// Round 3
// 807.785 us; speedup vs baseline: 3.9862x; 1.8102x over previous
//
#include <hip/hip_runtime.h>

#define NF 64

// tanhshrink(x) = x - tanh(x);  tanh(x) = 1 - 2/(exp(2x)+1)
__device__ __forceinline__ float ts_f(float x){
  float t = __expf(2.0f*x);
  float th = 1.0f - 2.0f*__builtin_amdgcn_rcpf(t + 1.0f);
  return x - th;
}
__device__ __forceinline__ float sigmoid_f(float x){
  return __builtin_amdgcn_rcpf(1.0f + __expf(-x));
}

// Per-node precompute of all edge-linear terms:
//   P[n] = [ nodes[n]@eW1[0:64]  + eb1 | nodes[n]@aW1[0:64]  + ab1 ]   (128 f)
//   Q[n] = [ nodes[n]@eW1[64:128]      | nodes[n]@aW1[64:128]      ]   (128 f)
// Then per edge: h1pre = P[r][0:64]+Q[c][0:64]+radial*eW1[128], a1pre =
// P[r][64:]+Q[c][64:]. Removes the 16K-FMA/edge phase-1 GEMM entirely.
__global__ __launch_bounds__(64) void egcl_pre(
    const float* __restrict__ nodes,
    const float* __restrict__ eW1, const float* __restrict__ eb1,
    const float* __restrict__ aW1, const float* __restrict__ ab1,
    float* __restrict__ P, float* __restrict__ Q, int N)
{
  const int i = blockIdx.x*64 + threadIdx.x;
  if (i >= N) return;
  const float* __restrict__ x = nodes + (size_t)i*NF;

  float acc[2*NF];
  #pragma unroll 1
  for (int pass=0; pass<2; pass++){
    const int kbase = pass*NF;
    if (pass == 0){
      #pragma unroll
      for (int j=0;j<NF;j++){ acc[j] = eb1[j]; acc[NF+j] = ab1[j]; }
    } else {
      #pragma unroll
      for (int j=0;j<2*NF;j++) acc[j] = 0.f;
    }
    #pragma unroll 1
    for (int q=0;q<16;q++){
      const float4 xv = *(const float4*)(x + 4*q);
      const float xs[4] = {xv.x,xv.y,xv.z,xv.w};
      #pragma unroll
      for (int u=0;u<4;u++){
        const int k = kbase + 4*q + u;
        const float xk = xs[u];
        const float* __restrict__ w1 = eW1 + k*NF;
        const float* __restrict__ w2 = aW1 + k*NF;
        #pragma unroll
        for (int j=0;j<NF;j++){
          acc[j]    = fmaf(xk, w1[j], acc[j]);
          acc[NF+j] = fmaf(xk, w2[j], acc[NF+j]);
        }
      }
    }
    float* __restrict__ dst = (pass==0 ? P : Q) + (size_t)i*(2*NF);
    #pragma unroll
    for (int q=0;q<32;q++)
      *(float4*)(dst + 4*q) = make_float4(acc[4*q],acc[4*q+1],acc[4*q+2],acc[4*q+3]);
  }
}

// One wave per block, one lane per edge. Phase 1 is now pure gather+add.
// Phases 2/3 (K=64 matvecs) keep k-outer / j-inner with wave-uniform weight
// loads and 64 VGPR accumulators. One 64x65 LDS tile serves as h1 scratch
// then edge_feat; the agg scatter reads it column-wise so each atomic
// instruction hits ONE node row with 64 consecutive dwords.
__global__ __launch_bounds__(64, 4) void egcl_edge(
    const float* __restrict__ coord,
    const int*   __restrict__ edges,
    const float* __restrict__ P, const float* __restrict__ Q,
    const float* __restrict__ eW1,                                   // radial row
    const float* __restrict__ eW2, const float* __restrict__ eb2,
    const float* __restrict__ aW2, const float* __restrict__ ab2,
    const float* __restrict__ cW1, const float* __restrict__ cb1,
    const float* __restrict__ cW2, const float* __restrict__ cb2,
    float* __restrict__ agg_out, float* __restrict__ coord_out,
    int E)
{
  __shared__ float buf[NF][NF+1];   // 16.64 KB: [feature][edge-lane]
  __shared__ int   rbuf[64];
  const int lane = threadIdx.x;
  const int e = blockIdx.x * 64 + lane;
  const bool valid = (e < E);
  const int el = valid ? e : (E - 1);

  const int r = edges[el];
  const int c = edges[E + el];
  rbuf[lane] = valid ? r : -1;

  const float rx = coord[3*r+0] - coord[3*c+0];
  const float ry = coord[3*r+1] - coord[3*c+1];
  const float rz = coord[3*r+2] - coord[3*c+2];
  const float radial = rx*rx + ry*ry + rz*rz;

  const float* __restrict__ Pr = P + (size_t)r * (2*NF);
  const float* __restrict__ Qc = Q + (size_t)c * (2*NF);
  const float* __restrict__ wrad = eW1 + 128*NF;

  // ---- attention gate: a1pre = P[r][64:128]+Q[c][64:128]; fully unrolled
  // so 32 gather loads are all outstanding together.
  float sp0=0.f, sp1=0.f, sp2=0.f, sp3=0.f;
  #pragma unroll
  for (int q=0;q<16;q++){
    const float4 pa = *(const float4*)(Pr + NF + 4*q);
    const float4 qa = *(const float4*)(Qc + NF + 4*q);
    sp0 += ts_f(pa.x+qa.x) * aW2[4*q+0];
    sp1 += ts_f(pa.y+qa.y) * aW2[4*q+1];
    sp2 += ts_f(pa.z+qa.z) * aW2[4*q+2];
    sp3 += ts_f(pa.w+qa.w) * aW2[4*q+3];
  }
  const float gate = sigmoid_f(sp0+sp1+sp2+sp3 + ab2[0]);

  // ---- h1 = ts(P[r][0:64]+Q[c][0:64]+radial*w128) -> LDS [k][lane]
  #pragma unroll
  for (int q=0;q<16;q++){
    const float4 ph = *(const float4*)(Pr + 4*q);
    const float4 qh = *(const float4*)(Qc + 4*q);
    buf[4*q+0][lane] = ts_f(fmaf(radial, wrad[4*q+0], ph.x+qh.x));
    buf[4*q+1][lane] = ts_f(fmaf(radial, wrad[4*q+1], ph.y+qh.y));
    buf[4*q+2][lane] = ts_f(fmaf(radial, wrad[4*q+2], ph.z+qh.z));
    buf[4*q+3][lane] = ts_f(fmaf(radial, wrad[4*q+3], ph.w+qh.w));
  }
  __syncthreads();

  // ---- phase 2: h2 preact (eW2, K=64)
  float acc2[NF];
  #pragma unroll
  for (int j=0;j<NF;j++) acc2[j] = eb2[j];
  #pragma unroll 1
  for (int kq=0;kq<16;kq++){
    #pragma unroll
    for (int ku=0;ku<4;ku++){
      const int k = kq*4+ku;
      const float hk = buf[k][lane];
      const float* __restrict__ w = eW2 + k*NF;
      #pragma unroll
      for (int j=0;j<NF;j++) acc2[j] = fmaf(hk, w[j], acc2[j]);
    }
  }
  __syncthreads();

  // ---- edge_feat = ts(h2)*gate -> LDS [j][lane]
  #pragma unroll
  for (int j=0;j<NF;j++) buf[j][lane] = ts_f(acc2[j]) * gate;
  __syncthreads();

  // ---- cooperative coalesced agg scatter, issued BEFORE phase-3 FMAs so
  // the fire-and-forget atomics drain under compute.
  #pragma unroll 1
  for (int eo=0;eo<64;eo++){
    const int rr = rbuf[eo];
    if (rr >= 0)
      atomicAdd(agg_out + (size_t)rr * NF + lane, buf[lane][eo]);
  }

  // ---- phase 3: c1 preact (cW1, K=64) from LDS ef, then cs = ts(c1).cW2 + cb2
  float acc3[NF];
  #pragma unroll
  for (int j=0;j<NF;j++) acc3[j] = cb1[j];
  #pragma unroll 1
  for (int kq=0;kq<16;kq++){
    #pragma unroll
    for (int ku=0;ku<4;ku++){
      const int k = kq*4+ku;
      const float ek = buf[k][lane];
      const float* __restrict__ w = cW1 + k*NF;
      #pragma unroll
      for (int j=0;j<NF;j++) acc3[j] = fmaf(ek, w[j], acc3[j]);
    }
  }
  float c0=0.f, c1s=0.f, c2s=0.f, c3s=0.f;
  #pragma unroll
  for (int j=0;j<NF;j+=4){
    c0  += ts_f(acc3[j+0]) * cW2[j+0];
    c1s += ts_f(acc3[j+1]) * cW2[j+1];
    c2s += ts_f(acc3[j+2]) * cW2[j+2];
    c3s += ts_f(acc3[j+3]) * cW2[j+3];
  }
  const float cs = c0+c1s+c2s+c3s + cb2[0];
  if (valid){
    atomicAdd(coord_out + 3*r + 0, rx * cs);
    atomicAdd(coord_out + 3*r + 1, ry * cs);
    atomicAdd(coord_out + 3*r + 2, rz * cs);
  }
}

// One lane per node. agg was accumulated (by atomics) directly into
// out_nodes; each lane reads its own row then overwrites it (no race).
__global__ __launch_bounds__(256, 2) void egcl_node(
    const float* __restrict__ nodes, const float* __restrict__ coord,
    const float* __restrict__ nW1, const float* __restrict__ nb1,
    const float* __restrict__ nW2, const float* __restrict__ nb2,
    float* __restrict__ out_nodes, float* __restrict__ out_coord,
    int N)
{
  __shared__ float buf[4][NF][NF+1];
  const int tid = threadIdx.x, wid = tid>>6, lane = tid&63;
  const int i = blockIdx.x*256 + tid;
  if (i >= N) return;

  float acc[NF];
  #pragma unroll
  for (int j=0;j<NF;j++) acc[j] = nb1[j];

  const float* __restrict__ xrow = nodes     + (size_t)i*NF;
  const float* __restrict__ grow = out_nodes + (size_t)i*NF - 64;  // agg, q>=16
  #pragma unroll 1
  for (int q=0;q<32;q++){
    const float* b = (q<16) ? xrow : grow;
    const float4 xv = *(const float4*)(b + 4*q);
    const float xs[4] = {xv.x,xv.y,xv.z,xv.w};
    #pragma unroll
    for (int u=0;u<4;u++){
      const int k = 4*q+u;
      const float xk = xs[u];
      const float* __restrict__ w = nW1 + k*NF;
      #pragma unroll
      for (int j=0;j<NF;j++) acc[j] = fmaf(xk, w[j], acc[j]);
    }
  }

  #pragma unroll
  for (int j=0;j<NF;j++) buf[wid][j][lane] = ts_f(acc[j]);

  float acc2[NF];
  #pragma unroll
  for (int j=0;j<NF;j++) acc2[j] = nb2[j];
  #pragma unroll 1
  for (int kq=0;kq<16;kq++){
    #pragma unroll
    for (int ku=0;ku<4;ku++){
      const int k = kq*4+ku;
      const float mk = buf[wid][k][lane];
      const float* __restrict__ w = nW2 + k*NF;
      #pragma unroll
      for (int j=0;j<NF;j++) acc2[j] = fmaf(mk, w[j], acc2[j]);
    }
  }

  float* __restrict__ orow = out_nodes + (size_t)i*NF;
  #pragma unroll
  for (int q=0;q<16;q++){
    const float4 xv = *(const float4*)(xrow + 4*q);
    float4 o;
    o.x = xv.x + acc2[4*q+0];
    o.y = xv.y + acc2[4*q+1];
    o.z = xv.z + acc2[4*q+2];
    o.w = xv.w + acc2[4*q+3];
    *(float4*)(orow + 4*q) = o;
  }

  const int b3 = 3*i;
  out_coord[b3+0] += coord[b3+0];
  out_coord[b3+1] += coord[b3+1];
  out_coord[b3+2] += coord[b3+2];
}

extern "C" void kernel_launch(void* const* d_in, const int* in_sizes, int n_in,
                              void* d_out, int out_size, void* d_ws, size_t ws_size,
                              hipStream_t stream)
{
  const float* nodes = (const float*)d_in[0];
  const float* coord = (const float*)d_in[1];
  const int*   edges = (const int*)  d_in[2];
  const float* eW1 = (const float*)d_in[3];
  const float* eb1 = (const float*)d_in[4];
  const float* eW2 = (const float*)d_in[5];
  const float* eb2 = (const float*)d_in[6];
  const float* aW1 = (const float*)d_in[7];
  const float* ab1 = (const float*)d_in[8];
  const float* aW2 = (const float*)d_in[9];
  const float* ab2 = (const float*)d_in[10];
  const float* nW1 = (const float*)d_in[11];
  const float* nb1 = (const float*)d_in[12];
  const float* nW2 = (const float*)d_in[13];
  const float* nb2 = (const float*)d_in[14];
  const float* cW1 = (const float*)d_in[15];
  const float* cb1 = (const float*)d_in[16];
  const float* cW2 = (const float*)d_in[17];
  const float* cb2 = (const float*)d_in[18];

  const int E = in_sizes[2] / 2;       // 800000
  const int N = in_sizes[0] / NF;      // 50000
  float* out_nodes = (float*)d_out;                      // also agg accumulator
  float* out_coord = out_nodes + (size_t)N * NF;         // also trans accumulator

  float* P = (float*)d_ws;                               // [N][128]
  float* Q = P + (size_t)N * (2*NF);                     // [N][128]

  hipMemsetAsync(d_out, 0, (size_t)out_size * sizeof(float), stream);

  egcl_pre<<<(N + 63)/64, 64, 0, stream>>>(nodes, eW1, eb1, aW1, ab1, P, Q, N);

  egcl_edge<<<(E + 63)/64, 64, 0, stream>>>(coord, edges, P, Q,
      eW1, eW2, eb2, aW2, ab2, cW1, cb1, cW2, cb2,
      out_nodes, out_coord, E);

  egcl_node<<<(N + 255)/256, 256, 0, stream>>>(nodes, coord,
      nW1, nb1, nW2, nb2, out_nodes, out_coord, N);
}

// Round 4
// 603.252 us; speedup vs baseline: 5.3377x; 1.3391x over previous
//
#include <hip/hip_runtime.h>

#define NF 64

typedef _Float16 half8 __attribute__((ext_vector_type(8)));
typedef float f32x4 __attribute__((ext_vector_type(4)));

// tanhshrink(x) = x - tanh(x);  tanh(x) = 1 - 2/(exp(2x)+1)
__device__ __forceinline__ float ts_f(float x){
  float t = __expf(2.0f*x);
  float th = 1.0f - 2.0f*__builtin_amdgcn_rcpf(t + 1.0f);
  return x - th;
}
__device__ __forceinline__ float sigmoid_f(float x){
  return __builtin_amdgcn_rcpf(1.0f + __expf(-x));
}

// Per-node precompute (f16 output: halves gather bytes, doubles cacheability):
//   P[n] = [ nodes[n]@eW1[0:64]+eb1 | nodes[n]@aW1[0:64]+ab1 ]   (128 f16)
//   Q[n] = [ nodes[n]@eW1[64:128]   | nodes[n]@aW1[64:128]   ]   (128 f16)
__global__ __launch_bounds__(64) void egcl_pre(
    const float* __restrict__ nodes,
    const float* __restrict__ eW1, const float* __restrict__ eb1,
    const float* __restrict__ aW1, const float* __restrict__ ab1,
    _Float16* __restrict__ P, _Float16* __restrict__ Q, int N)
{
  const int i = blockIdx.x*64 + threadIdx.x;
  if (i >= N) return;
  const float* __restrict__ x = nodes + (size_t)i*NF;

  float acc[2*NF];
  #pragma unroll 1
  for (int pass=0; pass<2; pass++){
    const int kbase = pass*NF;
    if (pass == 0){
      #pragma unroll
      for (int j=0;j<NF;j++){ acc[j] = eb1[j]; acc[NF+j] = ab1[j]; }
    } else {
      #pragma unroll
      for (int j=0;j<2*NF;j++) acc[j] = 0.f;
    }
    #pragma unroll 1
    for (int qq=0;qq<16;qq++){
      const float4 xv = *(const float4*)(x + 4*qq);
      const float xs[4] = {xv.x,xv.y,xv.z,xv.w};
      #pragma unroll
      for (int u=0;u<4;u++){
        const int k = kbase + 4*qq + u;
        const float xk = xs[u];
        const float* __restrict__ w1 = eW1 + k*NF;
        const float* __restrict__ w2 = aW1 + k*NF;
        #pragma unroll
        for (int j=0;j<NF;j++){
          acc[j]    = fmaf(xk, w1[j], acc[j]);
          acc[NF+j] = fmaf(xk, w2[j], acc[NF+j]);
        }
      }
    }
    _Float16* __restrict__ dst = (pass==0 ? P : Q) + (size_t)i*(2*NF);
    #pragma unroll
    for (int g=0;g<16;g++){
      half8 hv;
      #pragma unroll
      for (int j=0;j<8;j++) hv[j] = (_Float16)acc[8*g+j];
      *(half8*)(dst + 8*g) = hv;
    }
  }
}

// Transpose+cast weights for MFMA B-operand: Wt[n][k] f16 (row 128 B).
__global__ void egcl_prepw(const float* __restrict__ eW2, const float* __restrict__ cW1,
                           _Float16* __restrict__ W2t, _Float16* __restrict__ C1t)
{
  const int t = blockIdx.x*256 + threadIdx.x;
  if (t >= NF*NF) return;
  const int k = t >> 6, n = t & 63;
  W2t[n*NF + k] = (_Float16)eW2[k*NF + n];
  C1t[n*NF + k] = (_Float16)cW1[k*NF + n];
}

// One wave per block, lane=edge for pointwise parts; phases 2/3 are per-wave
// 64x64x64 GEMMs on mfma_f32_16x16x32_f16.
// A-frag: A[m=lane&15][k=(lane>>4)*8+j]  (ds_read_b128 from tile[edge][feat])
// B-frag: B[k=(lane>>4)*8+j][n=lane&15]  (global dwordx4 from Wt[n][k])
// C/D   : row=(lane>>4)*4+reg, col=lane&15
__global__ __launch_bounds__(64, 4) void egcl_edge(
    const float* __restrict__ coord,
    const int*   __restrict__ edges,
    const _Float16* __restrict__ P, const _Float16* __restrict__ Q,
    const float* __restrict__ eW1,                       // radial row at +128*NF
    const _Float16* __restrict__ W2t, const float* __restrict__ eb2,
    const float* __restrict__ aW2, const float* __restrict__ ab2,
    const _Float16* __restrict__ C1t, const float* __restrict__ cb1,
    const float* __restrict__ cW2, const float* __restrict__ cb2,
    float* __restrict__ agg_out, float* __restrict__ coord_out,
    int E)
{
  __shared__ _Float16 tile[64][72];   // h1, then ef  [edge][feat]
  __shared__ float gbuf[64];
  __shared__ float csbuf[64];
  __shared__ int   rbuf[64];

  const int lane = threadIdx.x;
  const int p = lane & 15, q = lane >> 4;
  const int e = blockIdx.x * 64 + lane;
  const bool valid = (e < E);
  const int el = valid ? e : (E - 1);

  const int r = edges[el];
  const int c = edges[E + el];
  rbuf[lane] = valid ? r : -1;

  const float rx = coord[3*r+0] - coord[3*c+0];
  const float ry = coord[3*r+1] - coord[3*c+1];
  const float rz = coord[3*r+2] - coord[3*c+2];
  const float radial = rx*rx + ry*ry + rz*rz;

  const _Float16* __restrict__ Pr = P + (size_t)r * 128;
  const _Float16* __restrict__ Qc = Q + (size_t)c * 128;
  const float* __restrict__ wrad = eW1 + 128*NF;

  // ---- attention gate (lane = own edge)
  float sp0=0.f, sp1=0.f;
  #pragma unroll
  for (int g=0;g<8;g++){
    const half8 pa = *(const half8*)(Pr + 64 + 8*g);
    const half8 qa = *(const half8*)(Qc + 64 + 8*g);
    #pragma unroll
    for (int j=0;j<8;j++){
      const float v = ts_f((float)pa[j] + (float)qa[j]);
      if (j & 1) sp1 = fmaf(v, aW2[8*g+j], sp1); else sp0 = fmaf(v, aW2[8*g+j], sp0);
    }
  }
  const float gate = sigmoid_f(sp0 + sp1 + ab2[0]);
  gbuf[lane] = gate;

  // ---- h1 = ts(Ph+Qh+radial*w128) -> tile[lane][*] f16
  #pragma unroll
  for (int g=0;g<8;g++){
    const half8 ph = *(const half8*)(Pr + 8*g);
    const half8 qh = *(const half8*)(Qc + 8*g);
    half8 hv;
    #pragma unroll
    for (int j=0;j<8;j++)
      hv[j] = (_Float16)ts_f(fmaf(radial, wrad[8*g+j], (float)ph[j] + (float)qh[j]));
    *(half8*)&tile[lane][8*g] = hv;
  }
  __syncthreads();

  // ---- phase 2 GEMM: h2pre = h1 @ eW2 + eb2
  half8 Bf[4][2];
  #pragma unroll
  for (int ni=0;ni<4;ni++)
    #pragma unroll
    for (int kt=0;kt<2;kt++)
      Bf[ni][kt] = *(const half8*)(W2t + (size_t)(16*ni + p)*NF + kt*32 + q*8);

  f32x4 acc[4][4];
  #pragma unroll
  for (int ni=0;ni<4;ni++){
    const float b = eb2[16*ni + p];
    #pragma unroll
    for (int mi=0;mi<4;mi++) acc[mi][ni] = (f32x4){b,b,b,b};
  }
  #pragma unroll
  for (int mi=0;mi<4;mi++){
    #pragma unroll
    for (int kt=0;kt<2;kt++){
      const half8 Af = *(const half8*)&tile[16*mi + p][kt*32 + q*8];
      #pragma unroll
      for (int ni=0;ni<4;ni++)
        acc[mi][ni] = __builtin_amdgcn_mfma_f32_16x16x32_f16(Af, Bf[ni][kt], acc[mi][ni], 0,0,0);
    }
  }
  __syncthreads();

  // ---- ef = ts(h2)*gate(row) -> tile (overwrite h1)
  #pragma unroll
  for (int mi=0;mi<4;mi++){
    #pragma unroll
    for (int rr=0;rr<4;rr++){
      const int row = 16*mi + 4*q + rr;
      const float gv = gbuf[row];
      #pragma unroll
      for (int ni=0;ni<4;ni++)
        tile[row][16*ni + p] = (_Float16)(ts_f(acc[mi][ni][rr]) * gv);
    }
  }
  __syncthreads();

  // ---- cooperative coalesced agg scatter (fire-and-forget atomics drain
  // under the phase-3 MFMAs below)
  #pragma unroll 1
  for (int eo=0;eo<64;eo++){
    const int rr = rbuf[eo];
    if (rr >= 0)
      atomicAdd(agg_out + (size_t)rr * NF + lane, (float)tile[eo][lane]);
  }

  // ---- phase 3 GEMM: c1pre = ef @ cW1 + cb1
  #pragma unroll
  for (int ni=0;ni<4;ni++)
    #pragma unroll
    for (int kt=0;kt<2;kt++)
      Bf[ni][kt] = *(const half8*)(C1t + (size_t)(16*ni + p)*NF + kt*32 + q*8);
  #pragma unroll
  for (int ni=0;ni<4;ni++){
    const float b = cb1[16*ni + p];
    #pragma unroll
    for (int mi=0;mi<4;mi++) acc[mi][ni] = (f32x4){b,b,b,b};
  }
  #pragma unroll
  for (int mi=0;mi<4;mi++){
    #pragma unroll
    for (int kt=0;kt<2;kt++){
      const half8 Af = *(const half8*)&tile[16*mi + p][kt*32 + q*8];
      #pragma unroll
      for (int ni=0;ni<4;ni++)
        acc[mi][ni] = __builtin_amdgcn_mfma_f32_16x16x32_f16(Af, Bf[ni][kt], acc[mi][ni], 0,0,0);
    }
  }

  // ---- cs = ts(c1) . cW2 + cb2 : partial dot in-lane, shfl_xor over the
  // 16-lane column group, one row per lane -> csbuf
  float part[4][4];   // [mi][rr]
  {
    float w2c[4];
    #pragma unroll
    for (int ni=0;ni<4;ni++) w2c[ni] = cW2[16*ni + p];
    #pragma unroll
    for (int mi=0;mi<4;mi++)
      #pragma unroll
      for (int rr=0;rr<4;rr++){
        float s = 0.f;
        #pragma unroll
        for (int ni=0;ni<4;ni++) s = fmaf(ts_f(acc[mi][ni][rr]), w2c[ni], s);
        part[mi][rr] = s;
      }
  }
  #pragma unroll
  for (int mask=1; mask<16; mask<<=1)
    #pragma unroll
    for (int mi=0;mi<4;mi++)
      #pragma unroll
      for (int rr=0;rr<4;rr++)
        part[mi][rr] += __shfl_xor(part[mi][rr], mask);

  // lane p writes row 16*(p>>2) + 4*q + (p&3)
  {
    float v = 0.f;
    #pragma unroll
    for (int mi=0;mi<4;mi++)
      #pragma unroll
      for (int rr=0;rr<4;rr++)
        if (((p>>2)==mi) & ((p&3)==rr)) v = part[mi][rr];
    csbuf[16*(p>>2) + 4*q + (p&3)] = v + cb2[0];
  }
  __syncthreads();

  if (valid){
    const float cs = csbuf[lane];
    atomicAdd(coord_out + 3*r + 0, rx * cs);
    atomicAdd(coord_out + 3*r + 1, ry * cs);
    atomicAdd(coord_out + 3*r + 2, rz * cs);
  }
}

// One lane per node. agg was accumulated (by atomics) directly into
// out_nodes; each lane reads its own row then overwrites it (no race).
__global__ __launch_bounds__(256, 2) void egcl_node(
    const float* __restrict__ nodes, const float* __restrict__ coord,
    const float* __restrict__ nW1, const float* __restrict__ nb1,
    const float* __restrict__ nW2, const float* __restrict__ nb2,
    float* __restrict__ out_nodes, float* __restrict__ out_coord,
    int N)
{
  __shared__ float buf[4][NF][NF+1];
  const int tid = threadIdx.x, wid = tid>>6, lane = tid&63;
  const int i = blockIdx.x*256 + tid;
  if (i >= N) return;

  float acc[NF];
  #pragma unroll
  for (int j=0;j<NF;j++) acc[j] = nb1[j];

  const float* __restrict__ xrow = nodes     + (size_t)i*NF;
  const float* __restrict__ grow = out_nodes + (size_t)i*NF - 64;  // agg, q>=16
  #pragma unroll 1
  for (int qq=0;qq<32;qq++){
    const float* b = (qq<16) ? xrow : grow;
    const float4 xv = *(const float4*)(b + 4*qq);
    const float xs[4] = {xv.x,xv.y,xv.z,xv.w};
    #pragma unroll
    for (int u=0;u<4;u++){
      const int k = 4*qq+u;
      const float xk = xs[u];
      const float* __restrict__ w = nW1 + k*NF;
      #pragma unroll
      for (int j=0;j<NF;j++) acc[j] = fmaf(xk, w[j], acc[j]);
    }
  }

  #pragma unroll
  for (int j=0;j<NF;j++) buf[wid][j][lane] = ts_f(acc[j]);

  float acc2[NF];
  #pragma unroll
  for (int j=0;j<NF;j++) acc2[j] = nb2[j];
  #pragma unroll 1
  for (int kq=0;kq<16;kq++){
    #pragma unroll
    for (int ku=0;ku<4;ku++){
      const int k = kq*4+ku;
      const float mk = buf[wid][k][lane];
      const float* __restrict__ w = nW2 + k*NF;
      #pragma unroll
      for (int j=0;j<NF;j++) acc2[j] = fmaf(mk, w[j], acc2[j]);
    }
  }

  float* __restrict__ orow = out_nodes + (size_t)i*NF;
  #pragma unroll
  for (int qq=0;qq<16;qq++){
    const float4 xv = *(const float4*)(xrow + 4*qq);
    float4 o;
    o.x = xv.x + acc2[4*qq+0];
    o.y = xv.y + acc2[4*qq+1];
    o.z = xv.z + acc2[4*qq+2];
    o.w = xv.w + acc2[4*qq+3];
    *(float4*)(orow + 4*qq) = o;
  }

  const int b3 = 3*i;
  out_coord[b3+0] += coord[b3+0];
  out_coord[b3+1] += coord[b3+1];
  out_coord[b3+2] += coord[b3+2];
}

extern "C" void kernel_launch(void* const* d_in, const int* in_sizes, int n_in,
                              void* d_out, int out_size, void* d_ws, size_t ws_size,
                              hipStream_t stream)
{
  const float* nodes = (const float*)d_in[0];
  const float* coord = (const float*)d_in[1];
  const int*   edges = (const int*)  d_in[2];
  const float* eW1 = (const float*)d_in[3];
  const float* eb1 = (const float*)d_in[4];
  const float* eW2 = (const float*)d_in[5];
  const float* eb2 = (const float*)d_in[6];
  const float* aW1 = (const float*)d_in[7];
  const float* ab1 = (const float*)d_in[8];
  const float* aW2 = (const float*)d_in[9];
  const float* ab2 = (const float*)d_in[10];
  const float* nW1 = (const float*)d_in[11];
  const float* nb1 = (const float*)d_in[12];
  const float* nW2 = (const float*)d_in[13];
  const float* nb2 = (const float*)d_in[14];
  const float* cW1 = (const float*)d_in[15];
  const float* cb1 = (const float*)d_in[16];
  const float* cW2 = (const float*)d_in[17];
  const float* cb2 = (const float*)d_in[18];

  const int E = in_sizes[2] / 2;       // 800000
  const int N = in_sizes[0] / NF;      // 50000
  float* out_nodes = (float*)d_out;                      // also agg accumulator
  float* out_coord = out_nodes + (size_t)N * NF;         // also trans accumulator

  _Float16* P   = (_Float16*)d_ws;                       // [N][128]
  _Float16* Q   = P + (size_t)N * 128;                   // [N][128]
  _Float16* W2t = Q + (size_t)N * 128;                   // [64][64]
  _Float16* C1t = W2t + NF*NF;                           // [64][64]

  hipMemsetAsync(d_out, 0, (size_t)out_size * sizeof(float), stream);

  egcl_pre<<<(N + 63)/64, 64, 0, stream>>>(nodes, eW1, eb1, aW1, ab1, P, Q, N);
  egcl_prepw<<<(NF*NF + 255)/256, 256, 0, stream>>>(eW2, cW1, W2t, C1t);

  egcl_edge<<<(E + 63)/64, 64, 0, stream>>>(coord, edges, P, Q,
      eW1, W2t, eb2, aW2, ab2, C1t, cb1, cW2, cb2,
      out_nodes, out_coord, E);

  egcl_node<<<(N + 255)/256, 256, 0, stream>>>(nodes, coord,
      nW1, nb1, nW2, nb2, out_nodes, out_coord, N);
}

// Round 5
// 404.594 us; speedup vs baseline: 7.9586x; 1.4910x over previous
//
#include <hip/hip_runtime.h>
#include <hip/hip_fp16.h>

#define NF 64

typedef _Float16 half8 __attribute__((ext_vector_type(8)));
typedef float f32x4 __attribute__((ext_vector_type(4)));

// tanhshrink(x) = x - tanh(x);  tanh(x) = 1 - 2/(exp(2x)+1)
__device__ __forceinline__ float ts_f(float x){
  float t = __expf(2.0f*x);
  float th = 1.0f - 2.0f*__builtin_amdgcn_rcpf(t + 1.0f);
  return x - th;
}
__device__ __forceinline__ float sigmoid_f(float x){
  return __builtin_amdgcn_rcpf(1.0f + __expf(-x));
}

// ---------------------------------------------------------------------------
// Weight prep: transpose+cast all MFMA B-operands to f16 [n][k] layout.
// W256t[256][64] = [eW1[0:64]|aW1[0:64]|eW1[64:128]|aW1[64:128]] columns.
// N1t[64][128] = nW1^T, W2t/C1t/N2t[64][64] = eW2^T/cW1^T/nW2^T.
__global__ void egcl_prepw(const float* __restrict__ eW1, const float* __restrict__ aW1,
                           const float* __restrict__ eW2, const float* __restrict__ cW1,
                           const float* __restrict__ nW1, const float* __restrict__ nW2,
                           _Float16* __restrict__ W256t, _Float16* __restrict__ N1t,
                           _Float16* __restrict__ W2t, _Float16* __restrict__ C1t,
                           _Float16* __restrict__ N2t)
{
  const int t = blockIdx.x*256 + threadIdx.x;
  if (t < 256*64){
    const int n = t >> 6, k = t & 63;
    float v;
    if      (n < 64)  v = eW1[k*NF + n];
    else if (n < 128) v = aW1[k*NF + (n-64)];
    else if (n < 192) v = eW1[(64+k)*NF + (n-128)];
    else              v = aW1[(64+k)*NF + (n-192)];
    W256t[t] = (_Float16)v;
  }
  if (t < 64*128){
    const int n = t >> 7, k = t & 127;
    N1t[t] = (_Float16)nW1[k*NF + n];
  }
  if (t < 64*64){
    const int n = t >> 6, k = t & 63;
    W2t[t] = (_Float16)eW2[k*NF + n];
    C1t[t] = (_Float16)cW1[k*NF + n];
    N2t[t] = (_Float16)nW2[k*NF + n];
  }
}

// ---------------------------------------------------------------------------
// Per-node precompute as MFMA GEMM, M=16 nodes per wave (3125 waves -> 3/SIMD).
//   [P|Q][n] f16 = nodes[n] @ W256 (+bias on P half)
// A-frag: A[m=lane&15][k=(lane>>4)*8+j] straight from global (cvt f32->f16).
__global__ __launch_bounds__(64, 8) void egcl_pre(
    const float* __restrict__ nodes,
    const float* __restrict__ eb1, const float* __restrict__ ab1,
    const _Float16* __restrict__ W256t,
    _Float16* __restrict__ P, _Float16* __restrict__ Q, int N)
{
  const int lane = threadIdx.x;
  const int p = lane & 15, q = lane >> 4;
  const int m0 = blockIdx.x * 16;
  const int row = m0 + p;

  const float* __restrict__ xr = nodes + (size_t)row * NF;
  half8 A[2];
  #pragma unroll
  for (int kt=0; kt<2; kt++){
    const float4 xa = *(const float4*)(xr + kt*32 + q*8);
    const float4 xb = *(const float4*)(xr + kt*32 + q*8 + 4);
    A[kt][0]=(_Float16)xa.x; A[kt][1]=(_Float16)xa.y; A[kt][2]=(_Float16)xa.z; A[kt][3]=(_Float16)xa.w;
    A[kt][4]=(_Float16)xb.x; A[kt][5]=(_Float16)xb.y; A[kt][6]=(_Float16)xb.z; A[kt][7]=(_Float16)xb.w;
  }

  #pragma unroll
  for (int ni=0; ni<16; ni++){
    float b = 0.f;
    if (ni < 4)       b = eb1[16*ni + p];
    else if (ni < 8)  b = ab1[16*(ni-4) + p];
    f32x4 acc = (f32x4){b,b,b,b};
    #pragma unroll
    for (int kt=0; kt<2; kt++){
      const half8 Bf = *(const half8*)(W256t + (size_t)(16*ni + p)*NF + kt*32 + q*8);
      acc = __builtin_amdgcn_mfma_f32_16x16x32_f16(A[kt], Bf, acc, 0,0,0);
    }
    // C/D: row = 4q+rr, col = p (within this ni tile)
    _Float16* __restrict__ dst = (ni < 8 ? P : Q);
    const int colbase = (ni & 7) * 16 + p;
    #pragma unroll
    for (int rr=0; rr<4; rr++)
      dst[(size_t)(m0 + 4*q + rr)*128 + colbase] = (_Float16)acc[rr];
  }
}

// ---------------------------------------------------------------------------
// Edge kernel: one wave per 64 edges. Phase 1 = gather P/Q + pointwise;
// phases 2/3 = per-wave 64x64x64 GEMMs on mfma_f32_16x16x32_f16.
// agg scatter uses packed-f16 atomics into aggh (half the atomic ops).
__global__ __launch_bounds__(64, 4) void egcl_edge(
    const float* __restrict__ coord,
    const int*   __restrict__ edges,
    const _Float16* __restrict__ P, const _Float16* __restrict__ Q,
    const float* __restrict__ eW1,                       // radial row at +128*NF
    const _Float16* __restrict__ W2t, const float* __restrict__ eb2,
    const float* __restrict__ aW2, const float* __restrict__ ab2,
    const _Float16* __restrict__ C1t, const float* __restrict__ cb1,
    const float* __restrict__ cW2, const float* __restrict__ cb2,
    _Float16* __restrict__ aggh, float* __restrict__ coord_out,
    int E)
{
  __shared__ _Float16 tile[64][72];   // h1, then ef  [edge][feat]
  __shared__ float gbuf[64];
  __shared__ float csbuf[64];
  __shared__ int   rbuf[64];

  const int lane = threadIdx.x;
  const int p = lane & 15, q = lane >> 4;
  const int e = blockIdx.x * 64 + lane;
  const bool valid = (e < E);
  const int el = valid ? e : (E - 1);

  const int r = edges[el];
  const int c = edges[E + el];
  rbuf[lane] = valid ? r : -1;

  const float rx = coord[3*r+0] - coord[3*c+0];
  const float ry = coord[3*r+1] - coord[3*c+1];
  const float rz = coord[3*r+2] - coord[3*c+2];
  const float radial = rx*rx + ry*ry + rz*rz;

  const _Float16* __restrict__ Pr = P + (size_t)r * 128;
  const _Float16* __restrict__ Qc = Q + (size_t)c * 128;
  const float* __restrict__ wrad = eW1 + 128*NF;

  // prefetch phase-2 B-frags (independent of LDS) so they overlap the sync
  half8 Bf[4][2];
  #pragma unroll
  for (int ni=0;ni<4;ni++)
    #pragma unroll
    for (int kt=0;kt<2;kt++)
      Bf[ni][kt] = *(const half8*)(W2t + (size_t)(16*ni + p)*NF + kt*32 + q*8);

  // ---- attention gate (lane = own edge)
  float sp0=0.f, sp1=0.f;
  #pragma unroll
  for (int g=0;g<8;g++){
    const half8 pa = *(const half8*)(Pr + 64 + 8*g);
    const half8 qa = *(const half8*)(Qc + 64 + 8*g);
    #pragma unroll
    for (int j=0;j<8;j++){
      const float v = ts_f((float)pa[j] + (float)qa[j]);
      if (j & 1) sp1 = fmaf(v, aW2[8*g+j], sp1); else sp0 = fmaf(v, aW2[8*g+j], sp0);
    }
  }
  const float gate = sigmoid_f(sp0 + sp1 + ab2[0]);
  gbuf[lane] = gate;

  // ---- h1 = ts(Ph+Qh+radial*w128) -> tile[lane][*] f16
  #pragma unroll
  for (int g=0;g<8;g++){
    const half8 ph = *(const half8*)(Pr + 8*g);
    const half8 qh = *(const half8*)(Qc + 8*g);
    half8 hv;
    #pragma unroll
    for (int j=0;j<8;j++)
      hv[j] = (_Float16)ts_f(fmaf(radial, wrad[8*g+j], (float)ph[j] + (float)qh[j]));
    *(half8*)&tile[lane][8*g] = hv;
  }
  __syncthreads();

  // ---- phase 2 GEMM: h2pre = h1 @ eW2 + eb2
  f32x4 acc[4][4];
  #pragma unroll
  for (int ni=0;ni<4;ni++){
    const float b = eb2[16*ni + p];
    #pragma unroll
    for (int mi=0;mi<4;mi++) acc[mi][ni] = (f32x4){b,b,b,b};
  }
  #pragma unroll
  for (int mi=0;mi<4;mi++){
    #pragma unroll
    for (int kt=0;kt<2;kt++){
      const half8 Af = *(const half8*)&tile[16*mi + p][kt*32 + q*8];
      #pragma unroll
      for (int ni=0;ni<4;ni++)
        acc[mi][ni] = __builtin_amdgcn_mfma_f32_16x16x32_f16(Af, Bf[ni][kt], acc[mi][ni], 0,0,0);
    }
  }
  __syncthreads();

  // ---- ef = ts(h2)*gate(row) -> tile (overwrite h1)
  #pragma unroll
  for (int mi=0;mi<4;mi++){
    #pragma unroll
    for (int rr=0;rr<4;rr++){
      const int row = 16*mi + 4*q + rr;
      const float gv = gbuf[row];
      #pragma unroll
      for (int ni=0;ni<4;ni++)
        tile[row][16*ni + p] = (_Float16)(ts_f(acc[mi][ni][rr]) * gv);
    }
  }
  __syncthreads();

  // ---- cooperative agg scatter: packed-f16 atomics, 2 edges per iteration
  // (lane>>5 picks edge, lane&31 picks the half2). Fire-and-forget; drains
  // under the phase-3 MFMAs below.
  #pragma unroll 1
  for (int eo2=0; eo2<32; eo2++){
    const int eo = 2*eo2 + (lane >> 5);
    const int f2 = lane & 31;
    const int rr = rbuf[eo];
    const __half2 v = *(const __half2*)&tile[eo][2*f2];
    if (rr >= 0)
      unsafeAtomicAdd((__half2*)aggh + (size_t)rr*32 + f2, v);
  }

  // ---- phase 3 GEMM: c1pre = ef @ cW1 + cb1
  #pragma unroll
  for (int ni=0;ni<4;ni++)
    #pragma unroll
    for (int kt=0;kt<2;kt++)
      Bf[ni][kt] = *(const half8*)(C1t + (size_t)(16*ni + p)*NF + kt*32 + q*8);
  #pragma unroll
  for (int ni=0;ni<4;ni++){
    const float b = cb1[16*ni + p];
    #pragma unroll
    for (int mi=0;mi<4;mi++) acc[mi][ni] = (f32x4){b,b,b,b};
  }
  #pragma unroll
  for (int mi=0;mi<4;mi++){
    #pragma unroll
    for (int kt=0;kt<2;kt++){
      const half8 Af = *(const half8*)&tile[16*mi + p][kt*32 + q*8];
      #pragma unroll
      for (int ni=0;ni<4;ni++)
        acc[mi][ni] = __builtin_amdgcn_mfma_f32_16x16x32_f16(Af, Bf[ni][kt], acc[mi][ni], 0,0,0);
    }
  }

  // ---- cs = ts(c1) . cW2 + cb2 : in-lane partial, shfl_xor over 16-lane
  // column group, one row per lane -> csbuf
  float part[4][4];   // [mi][rr]
  {
    float w2c[4];
    #pragma unroll
    for (int ni=0;ni<4;ni++) w2c[ni] = cW2[16*ni + p];
    #pragma unroll
    for (int mi=0;mi<4;mi++)
      #pragma unroll
      for (int rr=0;rr<4;rr++){
        float s = 0.f;
        #pragma unroll
        for (int ni=0;ni<4;ni++) s = fmaf(ts_f(acc[mi][ni][rr]), w2c[ni], s);
        part[mi][rr] = s;
      }
  }
  #pragma unroll
  for (int mask=1; mask<16; mask<<=1)
    #pragma unroll
    for (int mi=0;mi<4;mi++)
      #pragma unroll
      for (int rr=0;rr<4;rr++)
        part[mi][rr] += __shfl_xor(part[mi][rr], mask);

  {
    float v = 0.f;
    #pragma unroll
    for (int mi=0;mi<4;mi++)
      #pragma unroll
      for (int rr=0;rr<4;rr++)
        if (((p>>2)==mi) & ((p&3)==rr)) v = part[mi][rr];
    csbuf[16*(p>>2) + 4*q + (p&3)] = v + cb2[0];
  }
  __syncthreads();

  if (valid){
    const float cs = csbuf[lane];
    atomicAdd(coord_out + 3*r + 0, rx * cs);
    atomicAdd(coord_out + 3*r + 1, ry * cs);
    atomicAdd(coord_out + 3*r + 2, rz * cs);
  }
}

// ---------------------------------------------------------------------------
// Node MLP as MFMA GEMM, M=16 nodes per wave. K=128 (x f32->f16 | agg f16),
// ts, K=64, residual write. Tiny LDS transpose tile between the GEMMs.
__global__ __launch_bounds__(64, 8) void egcl_node(
    const float* __restrict__ nodes, const float* __restrict__ coord,
    const _Float16* __restrict__ aggh,
    const _Float16* __restrict__ N1t, const float* __restrict__ nb1,
    const _Float16* __restrict__ N2t, const float* __restrict__ nb2,
    float* __restrict__ out_nodes, float* __restrict__ out_coord, int N)
{
  __shared__ _Float16 t2[16][72];
  const int lane = threadIdx.x;
  const int p = lane & 15, q = lane >> 4;
  const int m0 = blockIdx.x * 16;
  const int row = m0 + p;

  // A-frags for GEMM1 (K=128): kt 0,1 from x (cvt), kt 2,3 from agg f16
  half8 A[4];
  const float* __restrict__ xr = nodes + (size_t)row * NF;
  #pragma unroll
  for (int kt=0; kt<2; kt++){
    const float4 xa = *(const float4*)(xr + kt*32 + q*8);
    const float4 xb = *(const float4*)(xr + kt*32 + q*8 + 4);
    A[kt][0]=(_Float16)xa.x; A[kt][1]=(_Float16)xa.y; A[kt][2]=(_Float16)xa.z; A[kt][3]=(_Float16)xa.w;
    A[kt][4]=(_Float16)xb.x; A[kt][5]=(_Float16)xb.y; A[kt][6]=(_Float16)xb.z; A[kt][7]=(_Float16)xb.w;
  }
  const _Float16* __restrict__ ar = aggh + (size_t)row * NF;
  #pragma unroll
  for (int kt=2; kt<4; kt++)
    A[kt] = *(const half8*)(ar + (kt-2)*32 + q*8);

  f32x4 acc[4];
  #pragma unroll
  for (int ni=0;ni<4;ni++){
    const float b = nb1[16*ni + p];
    acc[ni] = (f32x4){b,b,b,b};
  }
  #pragma unroll
  for (int kt=0; kt<4; kt++){
    #pragma unroll
    for (int ni=0;ni<4;ni++){
      const half8 Bf = *(const half8*)(N1t + (size_t)(16*ni + p)*128 + kt*32 + q*8);
      acc[ni] = __builtin_amdgcn_mfma_f32_16x16x32_f16(A[kt], Bf, acc[ni], 0,0,0);
    }
  }

  // m = ts(...) -> LDS transpose tile [row 4q+rr][col 16ni+p]
  #pragma unroll
  for (int ni=0;ni<4;ni++)
    #pragma unroll
    for (int rr=0;rr<4;rr++)
      t2[4*q + rr][16*ni + p] = (_Float16)ts_f(acc[ni][rr]);
  __syncthreads();

  // GEMM2 (K=64)
  half8 A2[2];
  #pragma unroll
  for (int kt=0; kt<2; kt++)
    A2[kt] = *(const half8*)&t2[p][kt*32 + q*8];

  f32x4 acc2[4];
  #pragma unroll
  for (int ni=0;ni<4;ni++){
    const float b = nb2[16*ni + p];
    acc2[ni] = (f32x4){b,b,b,b};
  }
  #pragma unroll
  for (int kt=0; kt<2; kt++){
    #pragma unroll
    for (int ni=0;ni<4;ni++){
      const half8 Bf = *(const half8*)(N2t + (size_t)(16*ni + p)*NF + kt*32 + q*8);
      acc2[ni] = __builtin_amdgcn_mfma_f32_16x16x32_f16(A2[kt], Bf, acc2[ni], 0,0,0);
    }
  }

  // residual write: out[row2][col] = nodes[row2][col] + acc2
  #pragma unroll
  for (int ni=0;ni<4;ni++){
    #pragma unroll
    for (int rr=0;rr<4;rr++){
      const size_t idx = (size_t)(m0 + 4*q + rr)*NF + 16*ni + p;
      out_nodes[idx] = nodes[idx] + acc2[ni][rr];
    }
  }

  // coord residual: 16 nodes x 3 = 48 elems, lanes 0..47
  if (lane < 48)
    out_coord[(size_t)m0*3 + lane] += coord[(size_t)m0*3 + lane];
}

// ---------------------------------------------------------------------------
extern "C" void kernel_launch(void* const* d_in, const int* in_sizes, int n_in,
                              void* d_out, int out_size, void* d_ws, size_t ws_size,
                              hipStream_t stream)
{
  const float* nodes = (const float*)d_in[0];
  const float* coord = (const float*)d_in[1];
  const int*   edges = (const int*)  d_in[2];
  const float* eW1 = (const float*)d_in[3];
  const float* eb1 = (const float*)d_in[4];
  const float* eW2 = (const float*)d_in[5];
  const float* eb2 = (const float*)d_in[6];
  const float* aW1 = (const float*)d_in[7];
  const float* ab1 = (const float*)d_in[8];
  const float* aW2 = (const float*)d_in[9];
  const float* ab2 = (const float*)d_in[10];
  const float* nW1 = (const float*)d_in[11];
  const float* nb1 = (const float*)d_in[12];
  const float* nW2 = (const float*)d_in[13];
  const float* nb2 = (const float*)d_in[14];
  const float* cW1 = (const float*)d_in[15];
  const float* cb1 = (const float*)d_in[16];
  const float* cW2 = (const float*)d_in[17];
  const float* cb2 = (const float*)d_in[18];

  const int E = in_sizes[2] / 2;       // 800000
  const int N = in_sizes[0] / NF;      // 50000
  float* out_nodes = (float*)d_out;
  float* out_coord = out_nodes + (size_t)N * NF;   // trans accumulator + residual

  _Float16* P     = (_Float16*)d_ws;               // [N][128]
  _Float16* Q     = P + (size_t)N * 128;           // [N][128]
  _Float16* aggh  = Q + (size_t)N * 128;           // [N][64]
  _Float16* W256t = aggh + (size_t)N * 64;         // [256][64]
  _Float16* N1t   = W256t + 256*64;                // [64][128]
  _Float16* W2t   = N1t + 64*128;                  // [64][64]
  _Float16* C1t   = W2t + 64*64;
  _Float16* N2t   = C1t + 64*64;

  hipMemsetAsync(d_out, 0, (size_t)out_size * sizeof(float), stream);
  hipMemsetAsync(aggh, 0, (size_t)N * 64 * sizeof(_Float16), stream);

  egcl_prepw<<<(256*64 + 255)/256, 256, 0, stream>>>(eW1, aW1, eW2, cW1, nW1, nW2,
      W256t, N1t, W2t, C1t, N2t);

  egcl_pre<<<(N + 15)/16, 64, 0, stream>>>(nodes, eb1, ab1, W256t, P, Q, N);

  egcl_edge<<<(E + 63)/64, 64, 0, stream>>>(coord, edges, P, Q,
      eW1, W2t, eb2, aW2, ab2, C1t, cb1, cW2, cb2,
      aggh, out_coord, E);

  egcl_node<<<(N + 15)/16, 64, 0, stream>>>(nodes, coord, aggh,
      N1t, nb1, N2t, nb2, out_nodes, out_coord, N);
}